// Round 1
// baseline (2532.580 us; speedup 1.0000x reference)
//
#include <hip/hip_runtime.h>
#include <hip/hip_bf16.h>

#define ALPHA_F 0.1f
#define KSTEPS 10

typedef __attribute__((ext_vector_type(8))) short bf16x8;
typedef __attribute__((ext_vector_type(4))) float f32x4;

__device__ __forceinline__ unsigned short f2bf(float f) {
  union { float f; unsigned int u; } v; v.f = f;
  unsigned int u = v.u;
  u += 0x7FFFu + ((u >> 16) & 1u);   // round-to-nearest-even
  return (unsigned short)(u >> 16);
}

// ---------------- CSR build ----------------
__global__ void k_count(const int* __restrict__ dst, int E, int* __restrict__ counts) {
  int i = blockIdx.x * 256 + threadIdx.x;
  if (i < E) atomicAdd(&counts[dst[i]], 1);
}

__global__ void k_dis(const int* __restrict__ counts, float* __restrict__ dis, int N) {
  int i = blockIdx.x * 256 + threadIdx.x;
  if (i < N) dis[i] = rsqrtf((float)(counts[i] + 1));  // +1 self-loop, always > 0
}

#define SCH 512
__global__ void k_scan1(const int* __restrict__ counts, int* __restrict__ bsum, int N, int NB) {
  int b = blockIdx.x * 256 + threadIdx.x;
  if (b >= NB) return;
  int base = b * SCH;
  int lim = min(SCH, N - base);
  int s = 0;
  for (int i = 0; i < lim; ++i) s += counts[base + i];
  bsum[b] = s;
}
__global__ void k_scan2(int* __restrict__ bsum, int NB, int* __restrict__ rowptr, int N) {
  if (threadIdx.x != 0 || blockIdx.x != 0) return;
  int run = 0;
  for (int b = 0; b < NB; ++b) { int t = bsum[b]; bsum[b] = run; run += t; }
  rowptr[N] = run;
}
__global__ void k_scan3(const int* __restrict__ counts, const int* __restrict__ bsum,
                        int* __restrict__ rowptr, int N, int NB) {
  int b = blockIdx.x * 256 + threadIdx.x;
  if (b >= NB) return;
  int base = b * SCH;
  int lim = min(SCH, N - base);
  int run = bsum[b];
  for (int i = 0; i < lim; ++i) { rowptr[base + i] = run; run += counts[base + i]; }
}

__global__ void k_fill(const int* __restrict__ src, const int* __restrict__ dstv, int E,
                       const int* __restrict__ rowptr, int* __restrict__ cursor,
                       const float* __restrict__ dis,
                       int* __restrict__ col, float* __restrict__ wgt) {
  int i = blockIdx.x * 256 + threadIdx.x;
  if (i >= E) return;
  int s = src[i], d = dstv[i];
  int pos = rowptr[d] + atomicAdd(&cursor[d], 1);
  col[pos] = s;
  wgt[pos] = dis[s] * dis[d];
}

// ---------------- weight transpose + bf16 convert: WT[n][k] = bf16(W[k][n]) ----------------
__global__ void k_wconv(const float* __restrict__ W, unsigned short* __restrict__ WT,
                        int Kd, int Nd) {
  int idx = blockIdx.x * 256 + threadIdx.x;
  if (idx >= Kd * Nd) return;
  int n = idx / Kd, k = idx % Kd;
  WT[idx] = f2bf(W[(size_t)k * Nd + n]);
}

// ---------------- bf16 MFMA GEMM: out[M][Nd] = A[M][Kd] * BT[Nd][Kd]^T + bias ----------------
// Block tile 64x64, BK=32, 4 waves (2x2), wave tile 32x32 (2x2 of 16x16x32 MFMA).
template<bool CONVERT_A, bool RELU, bool OUT_BF16>
__global__ __launch_bounds__(256)
void gemm_kernel(const void* __restrict__ Ag_, const unsigned short* __restrict__ BT,
                 const float* __restrict__ bias, void* __restrict__ out_,
                 int M, int Kd, int Nd) {
  __shared__ __align__(16) unsigned short As[64][40];   // +8 pad -> 2-way (free) conflicts
  __shared__ __align__(16) unsigned short Bs[64][40];
  const int t = threadIdx.x;
  const int m0 = blockIdx.x * 64;
  const int n0 = blockIdx.y * 64;
  const int lane = t & 63;
  const int w = t >> 6;
  const int wm = w >> 1, wn = w & 1;
  const int lrow = t >> 2;       // 0..63
  const int lcb = t & 3;         // 0..3, 8 elems each

  f32x4 acc[2][2] = {};

  for (int k0 = 0; k0 < Kd; k0 += 32) {
    // stage A tile [64 rows][32 k] (convert f32->bf16 if needed)
    {
      int gm = m0 + lrow;
      uint4 tv;
      unsigned short* tmp = (unsigned short*)&tv;
      if (CONVERT_A) {
        const float* A = (const float*)Ag_;
        if (gm < M) {
          const float* p = A + (size_t)gm * Kd + k0 + lcb * 8;
          float4 va = *(const float4*)p;
          float4 vb = *(const float4*)(p + 4);
          tmp[0] = f2bf(va.x); tmp[1] = f2bf(va.y); tmp[2] = f2bf(va.z); tmp[3] = f2bf(va.w);
          tmp[4] = f2bf(vb.x); tmp[5] = f2bf(vb.y); tmp[6] = f2bf(vb.z); tmp[7] = f2bf(vb.w);
        } else {
          tv = uint4{0, 0, 0, 0};
        }
      } else {
        const unsigned short* A = (const unsigned short*)Ag_;
        if (gm < M) tv = *(const uint4*)(A + (size_t)gm * Kd + k0 + lcb * 8);
        else        tv = uint4{0, 0, 0, 0};
      }
      *(uint4*)&As[lrow][lcb * 8] = tv;
    }
    // stage B tile [64 n][32 k] from pre-transposed bf16 BT
    {
      uint4 tv = *(const uint4*)(BT + (size_t)(n0 + lrow) * Kd + k0 + lcb * 8);
      *(uint4*)&Bs[lrow][lcb * 8] = tv;
    }
    __syncthreads();

    bf16x8 af[2], bfv[2];
#pragma unroll
    for (int mi = 0; mi < 2; ++mi)
      af[mi] = *(const bf16x8*)&As[(lane & 15) + 16 * mi + 32 * wm][(lane >> 4) * 8];
#pragma unroll
    for (int ni = 0; ni < 2; ++ni)
      bfv[ni] = *(const bf16x8*)&Bs[(lane & 15) + 16 * ni + 32 * wn][(lane >> 4) * 8];
#pragma unroll
    for (int mi = 0; mi < 2; ++mi)
#pragma unroll
      for (int ni = 0; ni < 2; ++ni)
        acc[mi][ni] = __builtin_amdgcn_mfma_f32_16x16x32_bf16(af[mi], bfv[ni], acc[mi][ni], 0, 0, 0);
    __syncthreads();
  }

  // epilogue: D row=(lane>>4)*4+j, col=lane&15 (verified m89 mapping)
  float* outf = (float*)out_;
  unsigned short* outb = (unsigned short*)out_;
#pragma unroll
  for (int mi = 0; mi < 2; ++mi) {
#pragma unroll
    for (int ni = 0; ni < 2; ++ni) {
      int gn = n0 + 32 * wn + 16 * ni + (lane & 15);
      float bv = bias[gn];
#pragma unroll
      for (int j = 0; j < 4; ++j) {
        int gm = m0 + 32 * wm + 16 * mi + (lane >> 4) * 4 + j;
        if (gm < M) {
          float v = acc[mi][ni][j] + bv;
          if (RELU) v = fmaxf(v, 0.f);
          if (OUT_BF16) outb[(size_t)gm * Nd + gn] = f2bf(v);
          else          outf[(size_t)gm * Nd + gn] = v;
        }
      }
    }
  }
}

// ---------------- PPR diffusion step: one wave per dst row, lane = column ----------------
__global__ __launch_bounds__(256)
void prop_kernel(const float* __restrict__ zin, const float* __restrict__ h,
                 float* __restrict__ zout, const int* __restrict__ rowptr,
                 const int* __restrict__ col, const float* __restrict__ wgt,
                 const float* __restrict__ dis, int N) {
  int wid = (blockIdx.x * 256 + threadIdx.x) >> 6;
  int lane = threadIdx.x & 63;
  if (wid >= N) return;
  int r = wid;
  float dr = dis[r];
  float acc = (dr * dr) * zin[(size_t)r * 64 + lane];   // self-loop term
  int start = rowptr[r], end = rowptr[r + 1];
  for (int e = start; e < end; e += 64) {
    int n_active = min(64, end - e);
    int c = 0; float ww = 0.f;
    if (lane < n_active) { c = col[e + lane]; ww = wgt[e + lane]; }
    for (int j = 0; j < n_active; ++j) {
      int cj = __shfl(c, j);
      float wj = __shfl(ww, j);
      acc += wj * zin[(size_t)cj * 64 + lane];
    }
  }
  zout[(size_t)r * 64 + lane] = ALPHA_F * h[(size_t)r * 64 + lane] + (1.f - ALPHA_F) * acc;
}

// ---------------- log_softmax over 64 cols: one wave per row ----------------
__global__ __launch_bounds__(256)
void k_lsm(const float* __restrict__ z, float* __restrict__ out, int N) {
  int wid = (blockIdx.x * 256 + threadIdx.x) >> 6;
  int lane = threadIdx.x & 63;
  if (wid >= N) return;
  float v = z[(size_t)wid * 64 + lane];
  float m = v;
#pragma unroll
  for (int off = 32; off; off >>= 1) m = fmaxf(m, __shfl_xor(m, off));
  float e = __expf(v - m);
  float s = e;
#pragma unroll
  for (int off = 32; off; off >>= 1) s += __shfl_xor(s, off);
  out[(size_t)wid * 64 + lane] = v - m - __logf(s);
}

extern "C" void kernel_launch(void* const* d_in, const int* in_sizes, int n_in,
                              void* d_out, int out_size, void* d_ws, size_t ws_size,
                              hipStream_t stream) {
  const float* x  = (const float*)d_in[0];
  const int*   ei = (const int*)d_in[1];
  const float* W1 = (const float*)d_in[2];
  const float* b1 = (const float*)d_in[3];
  const float* W2 = (const float*)d_in[4];
  const float* b2 = (const float*)d_in[5];

  const int IN = 512, HID = 256, OUT = 64;
  const int N = in_sizes[0] / IN;
  const int E = in_sizes[1] / 2;
  const int* srcv = ei;
  const int* dstv = ei + E;

  char* p = (char*)d_ws;
  auto alloc = [&](size_t bytes) -> void* {
    void* r = (void*)p;
    p += (bytes + 255) & ~(size_t)255;
    return r;
  };
  int*   counts = (int*)alloc((size_t)N * 4);
  int*   cursor = (int*)alloc((size_t)N * 4);
  float* dis    = (float*)alloc((size_t)N * 4);
  int*   rowptr = (int*)alloc((size_t)(N + 1) * 4);
  const int NB = (N + SCH - 1) / SCH;
  int*   bsum   = (int*)alloc((size_t)NB * 4);
  int*   col    = (int*)alloc((size_t)E * 4);
  float* wgt    = (float*)alloc((size_t)E * 4);
  unsigned short* WT1 = (unsigned short*)alloc((size_t)IN * HID * 2);
  unsigned short* WT2 = (unsigned short*)alloc((size_t)HID * OUT * 2);
  float* h  = (float*)alloc((size_t)N * OUT * 4);
  float* zA = (float*)alloc((size_t)N * OUT * 4);
  float* zB = (float*)alloc((size_t)N * OUT * 4);
  // hid (bf16, N x 256) overlays zA+zB exactly (N*256*2 == 2 * N*64*4); dead before prop starts
  unsigned short* hidb = (unsigned short*)zA;

  hipMemsetAsync(counts, 0, (size_t)N * 4, stream);
  hipMemsetAsync(cursor, 0, (size_t)N * 4, stream);

  k_count<<<(E + 255) / 256, 256, 0, stream>>>(dstv, E, counts);
  k_dis<<<(N + 255) / 256, 256, 0, stream>>>(counts, dis, N);
  k_scan1<<<(NB + 255) / 256, 256, 0, stream>>>(counts, bsum, N, NB);
  k_scan2<<<1, 64, 0, stream>>>(bsum, NB, rowptr, N);
  k_scan3<<<(NB + 255) / 256, 256, 0, stream>>>(counts, bsum, rowptr, N, NB);
  k_fill<<<(E + 255) / 256, 256, 0, stream>>>(srcv, dstv, E, rowptr, cursor, dis, col, wgt);

  k_wconv<<<(IN * HID + 255) / 256, 256, 0, stream>>>(W1, WT1, IN, HID);
  k_wconv<<<(HID * OUT + 255) / 256, 256, 0, stream>>>(W2, WT2, HID, OUT);

  dim3 g1((N + 63) / 64, HID / 64);
  gemm_kernel<true, true, true><<<g1, 256, 0, stream>>>(x, WT1, b1, hidb, N, IN, HID);
  dim3 g2((N + 63) / 64, OUT / 64);
  gemm_kernel<false, false, false><<<g2, 256, 0, stream>>>(hidb, WT2, b2, h, N, HID, OUT);

  int pblocks = (N + 3) / 4;   // 4 waves (rows) per block
  const float* zin = h;
  float* zbuf[2] = { zA, zB };
  for (int it = 0; it < KSTEPS; ++it) {
    float* zout = zbuf[it & 1];
    prop_kernel<<<pblocks, 256, 0, stream>>>(zin, h, zout, rowptr, col, wgt, dis, N);
    zin = zout;
  }
  k_lsm<<<pblocks, 256, 0, stream>>>(zin, (float*)d_out, N);
}

// Round 2
// 1671.475 us; speedup vs baseline: 1.5152x; 1.5152x over previous
//
#include <hip/hip_runtime.h>
#include <hip/hip_bf16.h>

#define ALPHA_F 0.1f
#define KSTEPS 10

typedef __attribute__((ext_vector_type(8))) short bf16x8;
typedef __attribute__((ext_vector_type(4))) float f32x4;

__device__ __forceinline__ unsigned short f2bf(float f) {
  union { float f; unsigned int u; } v; v.f = f;
  unsigned int u = v.u;
  u += 0x7FFFu + ((u >> 16) & 1u);   // round-to-nearest-even
  return (unsigned short)(u >> 16);
}
__device__ __forceinline__ float bflo(unsigned int u) { return __uint_as_float(u << 16); }
__device__ __forceinline__ float bfhi(unsigned int u) { return __uint_as_float(u & 0xFFFF0000u); }

// ---------------- CSR build ----------------
__global__ void k_count(const int* __restrict__ dst, int E, int* __restrict__ counts) {
  int i = blockIdx.x * 256 + threadIdx.x;
  if (i < E) atomicAdd(&counts[dst[i]], 1);
}

__global__ void k_dis(const int* __restrict__ counts, float* __restrict__ dis, int N) {
  int i = blockIdx.x * 256 + threadIdx.x;
  if (i < N) dis[i] = rsqrtf((float)(counts[i] + 1));  // +1 self-loop, always > 0
}

#define SCH 512
__global__ void k_scan1(const int* __restrict__ counts, int* __restrict__ bsum, int N, int NB) {
  int b = blockIdx.x * 256 + threadIdx.x;
  if (b >= NB) return;
  int base = b * SCH;
  int lim = min(SCH, N - base);
  int s = 0;
  for (int i = 0; i < lim; ++i) s += counts[base + i];
  bsum[b] = s;
}
__global__ void k_scan2(int* __restrict__ bsum, int NB, int* __restrict__ rowptr, int N) {
  if (threadIdx.x != 0 || blockIdx.x != 0) return;
  int run = 0;
  for (int b = 0; b < NB; ++b) { int t = bsum[b]; bsum[b] = run; run += t; }
  rowptr[N] = run;
}
__global__ void k_scan3(const int* __restrict__ counts, const int* __restrict__ bsum,
                        int* __restrict__ rowptr, int N, int NB) {
  int b = blockIdx.x * 256 + threadIdx.x;
  if (b >= NB) return;
  int base = b * SCH;
  int lim = min(SCH, N - base);
  int run = bsum[b];
  for (int i = 0; i < lim; ++i) { rowptr[base + i] = run; run += counts[base + i]; }
}

// fill: one packed 8B store per edge; counts doubles as cursor (atomicSub)
__global__ void k_fill(const int* __restrict__ src, const int* __restrict__ dstv, int E,
                       const int* __restrict__ rowptr, int* __restrict__ counts,
                       const float* __restrict__ dis, int2* __restrict__ edges) {
  int i = blockIdx.x * 256 + threadIdx.x;
  if (i >= E) return;
  int s = src[i], d = dstv[i];
  int pos = rowptr[d] + atomicSub(&counts[d], 1) - 1;
  edges[pos] = make_int2(s, __float_as_int(dis[s] * dis[d]));
}

// ---------------- weight transpose + bf16 convert: WT[n][k] = bf16(W[k][n]) ----------------
__global__ void k_wconv(const float* __restrict__ W, unsigned short* __restrict__ WT,
                        int Kd, int Nd) {
  int idx = blockIdx.x * 256 + threadIdx.x;
  if (idx >= Kd * Nd) return;
  int n = idx / Kd, k = idx % Kd;
  WT[idx] = f2bf(W[(size_t)k * Nd + n]);
}

// ---------------- bf16 MFMA GEMM: out[M][BN] = A[M][Kd] * BT[BN][Kd]^T + bias ----------------
// Block tile 64 x BN (BN == full Nd), BK=32, 4 waves (WR x WC).
template<int BN, int WR, int WC, bool CONVERT_A, bool RELU, bool OUT_BF16>
__global__ __launch_bounds__(256)
void gemm_kernel(const void* __restrict__ Ag_, const unsigned short* __restrict__ BT,
                 const float* __restrict__ bias, void* __restrict__ out_,
                 int M, int Kd) {
  constexpr int MF = 64 / (16 * WR);
  constexpr int NF = BN / (16 * WC);
  __shared__ __align__(16) unsigned short As[64][40];   // +8 pad -> 2-way (free)
  __shared__ __align__(16) unsigned short Bs[BN][40];
  const int t = threadIdx.x;
  const int m0 = blockIdx.x * 64;
  const int lane = t & 63;
  const int w = t >> 6;
  const int wr = w / WC, wc = w % WC;
  const int lrow = t >> 2;       // 0..63
  const int lcb = t & 3;         // 0..3, 8 elems each

  f32x4 acc[MF][NF] = {};

  for (int k0 = 0; k0 < Kd; k0 += 32) {
    // stage A tile [64 rows][32 k]
    {
      int gm = m0 + lrow;
      uint4 tv;
      unsigned short* tmp = (unsigned short*)&tv;
      if (CONVERT_A) {
        const float* A = (const float*)Ag_;
        if (gm < M) {
          const float* p = A + (size_t)gm * Kd + k0 + lcb * 8;
          float4 va = *(const float4*)p;
          float4 vb = *(const float4*)(p + 4);
          tmp[0] = f2bf(va.x); tmp[1] = f2bf(va.y); tmp[2] = f2bf(va.z); tmp[3] = f2bf(va.w);
          tmp[4] = f2bf(vb.x); tmp[5] = f2bf(vb.y); tmp[6] = f2bf(vb.z); tmp[7] = f2bf(vb.w);
        } else {
          tv = uint4{0, 0, 0, 0};
        }
      } else {
        const unsigned short* A = (const unsigned short*)Ag_;
        if (gm < M) tv = *(const uint4*)(A + (size_t)gm * Kd + k0 + lcb * 8);
        else        tv = uint4{0, 0, 0, 0};
      }
      *(uint4*)&As[lrow][lcb * 8] = tv;
    }
    // stage B tile [BN rows][32 k] from pre-transposed bf16 BT
#pragma unroll
    for (int i = 0; i < BN / 64; ++i) {
      int ch = t + 256 * i;
      int row = ch >> 2, kc = (ch & 3) * 8;
      *(uint4*)&Bs[row][kc] = *(const uint4*)(BT + (size_t)row * Kd + k0 + kc);
    }
    __syncthreads();

    bf16x8 af[MF], bfv[NF];
#pragma unroll
    for (int mi = 0; mi < MF; ++mi)
      af[mi] = *(const bf16x8*)&As[wr * MF * 16 + mi * 16 + (lane & 15)][(lane >> 4) * 8];
#pragma unroll
    for (int ni = 0; ni < NF; ++ni)
      bfv[ni] = *(const bf16x8*)&Bs[wc * NF * 16 + ni * 16 + (lane & 15)][(lane >> 4) * 8];
#pragma unroll
    for (int mi = 0; mi < MF; ++mi)
#pragma unroll
      for (int ni = 0; ni < NF; ++ni)
        acc[mi][ni] = __builtin_amdgcn_mfma_f32_16x16x32_bf16(af[mi], bfv[ni], acc[mi][ni], 0, 0, 0);
    __syncthreads();
  }

  // epilogue: D row=(lane>>4)*4+j, col=lane&15 (verified mapping)
  float* outf = (float*)out_;
  unsigned short* outb = (unsigned short*)out_;
#pragma unroll
  for (int mi = 0; mi < MF; ++mi) {
#pragma unroll
    for (int ni = 0; ni < NF; ++ni) {
      int gn = wc * NF * 16 + ni * 16 + (lane & 15);
      float bv = bias[gn];
#pragma unroll
      for (int j = 0; j < 4; ++j) {
        int gm = m0 + wr * MF * 16 + mi * 16 + (lane >> 4) * 4 + j;
        if (gm < M) {
          float v = acc[mi][ni][j] + bv;
          if (RELU) v = fmaxf(v, 0.f);
          if (OUT_BF16) outb[(size_t)gm * BN + gn] = f2bf(v);
          else          outf[(size_t)gm * BN + gn] = v;
        }
      }
    }
  }
}

// ---------------- PPR diffusion: one wave per dst row, 32 lanes x 2 cols, 2 edges/iter ----
// ZBF16: zin is bf16 [N][64] else f32. FINAL: fuse log_softmax, write f32.
template<bool ZBF16, bool FINAL>
__global__ __launch_bounds__(256)
void prop_kernel(const void* __restrict__ zin_, const float* __restrict__ h,
                 void* __restrict__ zout, const int* __restrict__ rowptr,
                 const int2* __restrict__ edges, const float* __restrict__ dis, int N) {
  int wid = (blockIdx.x * 256 + threadIdx.x) >> 6;
  int lane = threadIdx.x & 63;
  if (wid >= N) return;
  const int hi = lane >> 5;
  const int c2 = lane & 31;          // this lane's column pair {2c2, 2c2+1}
  int r = wid;
  float dr = dis[r];
  float sw = hi ? 0.f : dr * dr;     // self-loop counted once (hi==0 half)
  float ax, ay;
  if (ZBF16) {
    unsigned zz0 = *(const unsigned*)((const unsigned short*)zin_ + (size_t)r * 64 + 2 * c2);
    ax = sw * bflo(zz0); ay = sw * bfhi(zz0);
  } else {
    float2 z0 = *(const float2*)((const float*)zin_ + (size_t)r * 64 + 2 * c2);
    ax = sw * z0.x; ay = sw * z0.y;
  }
  int start = rowptr[r], end = rowptr[r + 1];
  for (int e = start; e < end; e += 64) {
    int na = end - e; if (na > 64) na = 64;
    int2 ed = make_int2(0, 0);                  // w==0 pad -> harmless
    if (lane < na) ed = edges[e + lane];
    for (int j = 0; j < na; j += 2) {
      int jj = j + hi;                          // half 0: edge j, half 1: edge j+1
      int cj = __shfl(ed.x, jj);
      float wj = __shfl(__int_as_float(ed.y), jj);
      if (ZBF16) {
        unsigned zz = *(const unsigned*)((const unsigned short*)zin_ + (size_t)cj * 64 + 2 * c2);
        ax += wj * bflo(zz); ay += wj * bfhi(zz);
      } else {
        float2 zz = *(const float2*)((const float*)zin_ + (size_t)cj * 64 + 2 * c2);
        ax += wj * zz.x; ay += wj * zz.y;
      }
    }
  }
  // combine the two half-wave partial sums
  ax += __shfl_xor(ax, 32);
  ay += __shfl_xor(ay, 32);
  float2 hv = *(const float2*)(h + (size_t)r * 64 + 2 * c2);
  float fx = ALPHA_F * hv.x + (1.f - ALPHA_F) * ax;
  float fy = ALPHA_F * hv.y + (1.f - ALPHA_F) * ay;
  if (!FINAL) {
    if (!hi) {
      unsigned o = (unsigned)f2bf(fx) | ((unsigned)f2bf(fy) << 16);
      *(unsigned*)((unsigned short*)zout + (size_t)r * 64 + 2 * c2) = o;
    }
  } else {
    float m = fmaxf(fx, fy);
#pragma unroll
    for (int off = 16; off; off >>= 1) m = fmaxf(m, __shfl_xor(m, off));
    float s = __expf(fx - m) + __expf(fy - m);
#pragma unroll
    for (int off = 16; off; off >>= 1) s += __shfl_xor(s, off);
    float ls = __logf(s);
    if (!hi) {
      float2 o = make_float2(fx - m - ls, fy - m - ls);
      *(float2*)((float*)zout + (size_t)r * 64 + 2 * c2) = o;
    }
  }
}

extern "C" void kernel_launch(void* const* d_in, const int* in_sizes, int n_in,
                              void* d_out, int out_size, void* d_ws, size_t ws_size,
                              hipStream_t stream) {
  const float* x  = (const float*)d_in[0];
  const int*   ei = (const int*)d_in[1];
  const float* W1 = (const float*)d_in[2];
  const float* b1 = (const float*)d_in[3];
  const float* W2 = (const float*)d_in[4];
  const float* b2 = (const float*)d_in[5];

  const int IN = 512, HID = 256, OUT = 64;
  const int N = in_sizes[0] / IN;
  const int E = in_sizes[1] / 2;
  const int* srcv = ei;
  const int* dstv = ei + E;

  char* p = (char*)d_ws;
  auto alloc = [&](size_t bytes) -> void* {
    void* r = (void*)p;
    p += (bytes + 255) & ~(size_t)255;
    return r;
  };
  int*   counts = (int*)alloc((size_t)N * 4);
  float* dis    = (float*)alloc((size_t)N * 4);
  int*   rowptr = (int*)alloc((size_t)(N + 1) * 4);
  const int NB = (N + SCH - 1) / SCH;
  int*   bsum   = (int*)alloc((size_t)NB * 4);
  int2*  edges  = (int2*)alloc((size_t)E * 8);
  unsigned short* WT1 = (unsigned short*)alloc((size_t)IN * HID * 2);
  unsigned short* WT2 = (unsigned short*)alloc((size_t)HID * OUT * 2);
  unsigned short* hidb = (unsigned short*)alloc((size_t)N * HID * 2);  // bf16 hidden
  float* h  = (float*)alloc((size_t)N * OUT * 4);
  // zA/zB (bf16 N x 64 each, 12.8 MB each) overlay hidb (51.2 MB): hidb is dead
  // once gemm2 completes, and prop only starts after gemm2 (stream-ordered).
  unsigned short* zA = hidb;
  unsigned short* zB = hidb + (size_t)N * OUT;

  hipMemsetAsync(counts, 0, (size_t)N * 4, stream);

  k_count<<<(E + 255) / 256, 256, 0, stream>>>(dstv, E, counts);
  k_dis<<<(N + 255) / 256, 256, 0, stream>>>(counts, dis, N);
  k_scan1<<<(NB + 255) / 256, 256, 0, stream>>>(counts, bsum, N, NB);
  k_scan2<<<1, 64, 0, stream>>>(bsum, NB, rowptr, N);
  k_scan3<<<(NB + 255) / 256, 256, 0, stream>>>(counts, bsum, rowptr, N, NB);
  k_fill<<<(E + 255) / 256, 256, 0, stream>>>(srcv, dstv, E, rowptr, counts, dis, edges);

  k_wconv<<<(IN * HID + 255) / 256, 256, 0, stream>>>(W1, WT1, IN, HID);
  k_wconv<<<(HID * OUT + 255) / 256, 256, 0, stream>>>(W2, WT2, HID, OUT);

  const int gblocks = (N + 63) / 64;
  // GEMM1: 64x256 block (full HID) so x is read exactly once; relu; bf16 out
  gemm_kernel<256, 1, 4, true, true, true><<<gblocks, 256, 0, stream>>>(
      x, WT1, b1, hidb, N, IN);
  // GEMM2: 64x64 block (full OUT); f32 out
  gemm_kernel<64, 2, 2, false, false, false><<<gblocks, 256, 0, stream>>>(
      hidb, WT2, b2, h, N, HID);

  const int pblocks = (N + 3) / 4;   // 4 waves (rows) per block
  // step 0 reads f32 h (z0 = h exactly); steps 1..8 read bf16; step 9 fuses lsm
  unsigned short* zcur = zA;
  prop_kernel<false, false><<<pblocks, 256, 0, stream>>>(h, h, zA, rowptr, edges, dis, N);
  for (int it = 1; it < KSTEPS - 1; ++it) {
    unsigned short* znext = (it & 1) ? zB : zA;
    prop_kernel<true, false><<<pblocks, 256, 0, stream>>>(zcur, h, znext, rowptr, edges, dis, N);
    zcur = znext;
  }
  prop_kernel<true, true><<<pblocks, 256, 0, stream>>>(zcur, h, d_out, rowptr, edges, dis, N);
}

// Round 3
// 1237.204 us; speedup vs baseline: 2.0470x; 1.3510x over previous
//
#include <hip/hip_runtime.h>
#include <hip/hip_bf16.h>

#define ALPHA_F 0.1f
#define KSTEPS 10

typedef __attribute__((ext_vector_type(8))) short bf16x8;
typedef __attribute__((ext_vector_type(4))) float f32x4;

__device__ __forceinline__ unsigned short f2bf(float f) {
  union { float f; unsigned int u; } v; v.f = f;
  unsigned int u = v.u;
  u += 0x7FFFu + ((u >> 16) & 1u);   // round-to-nearest-even
  return (unsigned short)(u >> 16);
}
__device__ __forceinline__ float bflo(unsigned int u) { return __uint_as_float(u << 16); }
__device__ __forceinline__ float bfhi(unsigned int u) { return __uint_as_float(u & 0xFFFF0000u); }

// ---------------- CSR build ----------------
__global__ void k_count(const int* __restrict__ dst, int E, int* __restrict__ counts) {
  int i = blockIdx.x * 256 + threadIdx.x;
  if (i < E) atomicAdd(&counts[dst[i]], 1);
}

__global__ void k_dis(const int* __restrict__ counts, float* __restrict__ dis, int N) {
  int i = blockIdx.x * 256 + threadIdx.x;
  if (i < N) dis[i] = rsqrtf((float)(counts[i] + 1));  // +1 self-loop, always > 0
}

#define SCH 512
__global__ void k_scan1(const int* __restrict__ counts, int* __restrict__ bsum, int N, int NB) {
  int b = blockIdx.x * 256 + threadIdx.x;
  if (b >= NB) return;
  int base = b * SCH;
  int lim = min(SCH, N - base);
  int s = 0;
  for (int i = 0; i < lim; ++i) s += counts[base + i];
  bsum[b] = s;
}
__global__ void k_scan2(int* __restrict__ bsum, int NB, int* __restrict__ rowptr, int N) {
  if (threadIdx.x != 0 || blockIdx.x != 0) return;
  int run = 0;
  for (int b = 0; b < NB; ++b) { int t = bsum[b]; bsum[b] = run; run += t; }
  rowptr[N] = run;
}
__global__ void k_scan3(const int* __restrict__ counts, const int* __restrict__ bsum,
                        int* __restrict__ rowptr, int N, int NB) {
  int b = blockIdx.x * 256 + threadIdx.x;
  if (b >= NB) return;
  int base = b * SCH;
  int lim = min(SCH, N - base);
  int run = bsum[b];
  for (int i = 0; i < lim; ++i) { rowptr[base + i] = run; run += counts[base + i]; }
}

// fill: one packed 8B store per edge; counts doubles as cursor (atomicSub)
__global__ void k_fill(const int* __restrict__ src, const int* __restrict__ dstv, int E,
                       const int* __restrict__ rowptr, int* __restrict__ counts,
                       const float* __restrict__ dis, int2* __restrict__ edges) {
  int i = blockIdx.x * 256 + threadIdx.x;
  if (i >= E) return;
  int s = src[i], d = dstv[i];
  int pos = rowptr[d] + atomicSub(&counts[d], 1) - 1;
  edges[pos] = make_int2(s, __float_as_int(dis[s] * dis[d]));
}

// ---------------- weight transpose + bf16 convert: WT[n][k] = bf16(W[k][n]) ----------------
__global__ void k_wconv(const float* __restrict__ W, unsigned short* __restrict__ WT,
                        int Kd, int Nd) {
  int idx = blockIdx.x * 256 + threadIdx.x;
  if (idx >= Kd * Nd) return;
  int n = idx / Kd, k = idx % Kd;
  WT[idx] = f2bf(W[(size_t)k * Nd + n]);
}

// ---------------- bf16 MFMA GEMM: out[M][BN] = A[M][Kd] * BT[BN][Kd]^T + bias ----------------
template<int BN, int WR, int WC, bool CONVERT_A, bool RELU, bool OUT_BF16>
__global__ __launch_bounds__(256)
void gemm_kernel(const void* __restrict__ Ag_, const unsigned short* __restrict__ BT,
                 const float* __restrict__ bias, void* __restrict__ out_,
                 int M, int Kd) {
  constexpr int MF = 64 / (16 * WR);
  constexpr int NF = BN / (16 * WC);
  __shared__ __align__(16) unsigned short As[64][40];
  __shared__ __align__(16) unsigned short Bs[BN][40];
  const int t = threadIdx.x;
  const int m0 = blockIdx.x * 64;
  const int lane = t & 63;
  const int w = t >> 6;
  const int wr = w / WC, wc = w % WC;
  const int lrow = t >> 2;
  const int lcb = t & 3;

  f32x4 acc[MF][NF] = {};

  for (int k0 = 0; k0 < Kd; k0 += 32) {
    {
      int gm = m0 + lrow;
      uint4 tv;
      unsigned short* tmp = (unsigned short*)&tv;
      if (CONVERT_A) {
        const float* A = (const float*)Ag_;
        if (gm < M) {
          const float* p = A + (size_t)gm * Kd + k0 + lcb * 8;
          float4 va = *(const float4*)p;
          float4 vb = *(const float4*)(p + 4);
          tmp[0] = f2bf(va.x); tmp[1] = f2bf(va.y); tmp[2] = f2bf(va.z); tmp[3] = f2bf(va.w);
          tmp[4] = f2bf(vb.x); tmp[5] = f2bf(vb.y); tmp[6] = f2bf(vb.z); tmp[7] = f2bf(vb.w);
        } else {
          tv = uint4{0, 0, 0, 0};
        }
      } else {
        const unsigned short* A = (const unsigned short*)Ag_;
        if (gm < M) tv = *(const uint4*)(A + (size_t)gm * Kd + k0 + lcb * 8);
        else        tv = uint4{0, 0, 0, 0};
      }
      *(uint4*)&As[lrow][lcb * 8] = tv;
    }
#pragma unroll
    for (int i = 0; i < BN / 64; ++i) {
      int ch = t + 256 * i;
      int row = ch >> 2, kc = (ch & 3) * 8;
      *(uint4*)&Bs[row][kc] = *(const uint4*)(BT + (size_t)row * Kd + k0 + kc);
    }
    __syncthreads();

    bf16x8 af[MF], bfv[NF];
#pragma unroll
    for (int mi = 0; mi < MF; ++mi)
      af[mi] = *(const bf16x8*)&As[wr * MF * 16 + mi * 16 + (lane & 15)][(lane >> 4) * 8];
#pragma unroll
    for (int ni = 0; ni < NF; ++ni)
      bfv[ni] = *(const bf16x8*)&Bs[wc * NF * 16 + ni * 16 + (lane & 15)][(lane >> 4) * 8];
#pragma unroll
    for (int mi = 0; mi < MF; ++mi)
#pragma unroll
      for (int ni = 0; ni < NF; ++ni)
        acc[mi][ni] = __builtin_amdgcn_mfma_f32_16x16x32_bf16(af[mi], bfv[ni], acc[mi][ni], 0, 0, 0);
    __syncthreads();
  }

  float* outf = (float*)out_;
  unsigned short* outb = (unsigned short*)out_;
#pragma unroll
  for (int mi = 0; mi < MF; ++mi) {
#pragma unroll
    for (int ni = 0; ni < NF; ++ni) {
      int gn = wc * NF * 16 + ni * 16 + (lane & 15);
      float bv = bias[gn];
#pragma unroll
      for (int j = 0; j < 4; ++j) {
        int gm = m0 + wr * MF * 16 + mi * 16 + (lane >> 4) * 4 + j;
        if (gm < M) {
          float v = acc[mi][ni][j] + bv;
          if (RELU) v = fmaxf(v, 0.f);
          if (OUT_BF16) outb[(size_t)gm * BN + gn] = f2bf(v);
          else          outf[(size_t)gm * BN + gn] = v;
        }
      }
    }
  }
}

// ---------------- PPR diffusion: one wave per dst row ----------------
// 8 lanes per edge (16B z-slice each), 8 edges per wave-iteration.
// lane: g = lane>>3 (edge subgroup), lg = lane&7 (col slice 8*lg..8*lg+7)
// ZBF16: zin is bf16 [N][64] else f32. FINAL: fuse log_softmax, write f32.
template<bool ZBF16, bool FINAL>
__global__ __launch_bounds__(256)
void prop_kernel(const void* __restrict__ zin_, const float* __restrict__ h,
                 void* __restrict__ zout, const int* __restrict__ rowptr,
                 const int2* __restrict__ edges, const float* __restrict__ dis, int N) {
  int wid = (blockIdx.x * 256 + threadIdx.x) >> 6;
  wid = __builtin_amdgcn_readfirstlane(wid);   // wave-uniform -> scalar loads below
  if (wid >= N) return;
  const int lane = threadIdx.x & 63;
  const int g  = lane >> 3;
  const int lg = lane & 7;
  const int r = wid;

  float acc[8] = {0.f, 0.f, 0.f, 0.f, 0.f, 0.f, 0.f, 0.f};
  const int start = rowptr[r], end = rowptr[r + 1];
  for (int e = start; e < end; e += 64) {
    int na = end - e; if (na > 64) na = 64;
    int2 ed = make_int2(0, 0);                 // pad: w==0 -> contributes 0
    if (lane < na) ed = edges[e + lane];
#pragma unroll 4
    for (int j = 0; j < na; j += 8) {
      int jj = j + g;                          // group g handles edge j+g
      int cj = __shfl(ed.x, jj);
      float wj = __shfl(__int_as_float(ed.y), jj);
      if (ZBF16) {
        uint4 zr = *(const uint4*)((const unsigned short*)zin_ + (size_t)cj * 64 + 8 * lg);
        acc[0] += wj * bflo(zr.x); acc[1] += wj * bfhi(zr.x);
        acc[2] += wj * bflo(zr.y); acc[3] += wj * bfhi(zr.y);
        acc[4] += wj * bflo(zr.z); acc[5] += wj * bfhi(zr.z);
        acc[6] += wj * bflo(zr.w); acc[7] += wj * bfhi(zr.w);
      } else {
        const float* zp = (const float*)zin_ + (size_t)cj * 64 + 8 * lg;
        float4 a = *(const float4*)zp;
        float4 b = *(const float4*)(zp + 4);
        acc[0] += wj * a.x; acc[1] += wj * a.y; acc[2] += wj * a.z; acc[3] += wj * a.w;
        acc[4] += wj * b.x; acc[5] += wj * b.y; acc[6] += wj * b.z; acc[7] += wj * b.w;
      }
    }
  }
  // combine the 8 edge-subgroups (bits 3..5 of lane)
#pragma unroll
  for (int k = 0; k < 8; ++k) {
    acc[k] += __shfl_xor(acc[k], 8);
    acc[k] += __shfl_xor(acc[k], 16);
    acc[k] += __shfl_xor(acc[k], 32);
  }

  // self-loop term + h blend (all lanes compute; groups hold replicated values)
  float dr = dis[r];
  float sw = dr * dr;
  float selfz[8];
  if (ZBF16) {
    uint4 zr = *(const uint4*)((const unsigned short*)zin_ + (size_t)r * 64 + 8 * lg);
    selfz[0] = bflo(zr.x); selfz[1] = bfhi(zr.x);
    selfz[2] = bflo(zr.y); selfz[3] = bfhi(zr.y);
    selfz[4] = bflo(zr.z); selfz[5] = bfhi(zr.z);
    selfz[6] = bflo(zr.w); selfz[7] = bfhi(zr.w);
  } else {
    const float* zp = (const float*)zin_ + (size_t)r * 64 + 8 * lg;
    float4 a = *(const float4*)zp; float4 b = *(const float4*)(zp + 4);
    selfz[0] = a.x; selfz[1] = a.y; selfz[2] = a.z; selfz[3] = a.w;
    selfz[4] = b.x; selfz[5] = b.y; selfz[6] = b.z; selfz[7] = b.w;
  }
  const float* hp = h + (size_t)r * 64 + 8 * lg;
  float4 ha = *(const float4*)hp;
  float4 hb = *(const float4*)(hp + 4);
  float f[8];
  f[0] = ALPHA_F * ha.x + (1.f - ALPHA_F) * (acc[0] + sw * selfz[0]);
  f[1] = ALPHA_F * ha.y + (1.f - ALPHA_F) * (acc[1] + sw * selfz[1]);
  f[2] = ALPHA_F * ha.z + (1.f - ALPHA_F) * (acc[2] + sw * selfz[2]);
  f[3] = ALPHA_F * ha.w + (1.f - ALPHA_F) * (acc[3] + sw * selfz[3]);
  f[4] = ALPHA_F * hb.x + (1.f - ALPHA_F) * (acc[4] + sw * selfz[4]);
  f[5] = ALPHA_F * hb.y + (1.f - ALPHA_F) * (acc[5] + sw * selfz[5]);
  f[6] = ALPHA_F * hb.z + (1.f - ALPHA_F) * (acc[6] + sw * selfz[6]);
  f[7] = ALPHA_F * hb.w + (1.f - ALPHA_F) * (acc[7] + sw * selfz[7]);

  if (!FINAL) {
    if (g == 0) {
      uint4 o;
      o.x = (unsigned)f2bf(f[0]) | ((unsigned)f2bf(f[1]) << 16);
      o.y = (unsigned)f2bf(f[2]) | ((unsigned)f2bf(f[3]) << 16);
      o.z = (unsigned)f2bf(f[4]) | ((unsigned)f2bf(f[5]) << 16);
      o.w = (unsigned)f2bf(f[6]) | ((unsigned)f2bf(f[7]) << 16);
      *(uint4*)((unsigned short*)zout + (size_t)r * 64 + 8 * lg) = o;
    }
  } else {
    float m = f[0];
#pragma unroll
    for (int k = 1; k < 8; ++k) m = fmaxf(m, f[k]);
    m = fmaxf(m, __shfl_xor(m, 1));
    m = fmaxf(m, __shfl_xor(m, 2));
    m = fmaxf(m, __shfl_xor(m, 4));
    float s = 0.f;
#pragma unroll
    for (int k = 0; k < 8; ++k) s += __expf(f[k] - m);
    s += __shfl_xor(s, 1);
    s += __shfl_xor(s, 2);
    s += __shfl_xor(s, 4);
    float ls = __logf(s);
    if (g == 0) {
      float* op = (float*)zout + (size_t)r * 64 + 8 * lg;
      float4 oa = make_float4(f[0] - m - ls, f[1] - m - ls, f[2] - m - ls, f[3] - m - ls);
      float4 ob = make_float4(f[4] - m - ls, f[5] - m - ls, f[6] - m - ls, f[7] - m - ls);
      *(float4*)op = oa;
      *(float4*)(op + 4) = ob;
    }
  }
}

extern "C" void kernel_launch(void* const* d_in, const int* in_sizes, int n_in,
                              void* d_out, int out_size, void* d_ws, size_t ws_size,
                              hipStream_t stream) {
  const float* x  = (const float*)d_in[0];
  const int*   ei = (const int*)d_in[1];
  const float* W1 = (const float*)d_in[2];
  const float* b1 = (const float*)d_in[3];
  const float* W2 = (const float*)d_in[4];
  const float* b2 = (const float*)d_in[5];

  const int IN = 512, HID = 256, OUT = 64;
  const int N = in_sizes[0] / IN;
  const int E = in_sizes[1] / 2;
  const int* srcv = ei;
  const int* dstv = ei + E;

  char* p = (char*)d_ws;
  auto alloc = [&](size_t bytes) -> void* {
    void* r = (void*)p;
    p += (bytes + 255) & ~(size_t)255;
    return r;
  };
  int*   counts = (int*)alloc((size_t)N * 4);
  float* dis    = (float*)alloc((size_t)N * 4);
  int*   rowptr = (int*)alloc((size_t)(N + 1) * 4);
  const int NB = (N + SCH - 1) / SCH;
  int*   bsum   = (int*)alloc((size_t)NB * 4);
  int2*  edges  = (int2*)alloc((size_t)E * 8);
  unsigned short* WT1 = (unsigned short*)alloc((size_t)IN * HID * 2);
  unsigned short* WT2 = (unsigned short*)alloc((size_t)HID * OUT * 2);
  unsigned short* hidb = (unsigned short*)alloc((size_t)N * HID * 2);
  float* h  = (float*)alloc((size_t)N * OUT * 4);
  // zA/zB (bf16 N x 64 each) overlay hidb: hidb is dead once gemm2 completes
  unsigned short* zA = hidb;
  unsigned short* zB = hidb + (size_t)N * OUT;

  hipMemsetAsync(counts, 0, (size_t)N * 4, stream);

  k_count<<<(E + 255) / 256, 256, 0, stream>>>(dstv, E, counts);
  k_dis<<<(N + 255) / 256, 256, 0, stream>>>(counts, dis, N);
  k_scan1<<<(NB + 255) / 256, 256, 0, stream>>>(counts, bsum, N, NB);
  k_scan2<<<1, 64, 0, stream>>>(bsum, NB, rowptr, N);
  k_scan3<<<(NB + 255) / 256, 256, 0, stream>>>(counts, bsum, rowptr, N, NB);
  k_fill<<<(E + 255) / 256, 256, 0, stream>>>(srcv, dstv, E, rowptr, counts, dis, edges);

  k_wconv<<<(IN * HID + 255) / 256, 256, 0, stream>>>(W1, WT1, IN, HID);
  k_wconv<<<(HID * OUT + 255) / 256, 256, 0, stream>>>(W2, WT2, HID, OUT);

  const int gblocks = (N + 63) / 64;
  gemm_kernel<256, 1, 4, true, true, true><<<gblocks, 256, 0, stream>>>(
      x, WT1, b1, hidb, N, IN);
  gemm_kernel<64, 2, 2, false, false, false><<<gblocks, 256, 0, stream>>>(
      hidb, WT2, b2, h, N, HID);

  const int pblocks = (N + 3) / 4;
  unsigned short* zcur = zA;
  prop_kernel<false, false><<<pblocks, 256, 0, stream>>>(h, h, zA, rowptr, edges, dis, N);
  for (int it = 1; it < KSTEPS - 1; ++it) {
    unsigned short* znext = (it & 1) ? zB : zA;
    prop_kernel<true, false><<<pblocks, 256, 0, stream>>>(zcur, h, znext, rowptr, edges, dis, N);
    zcur = znext;
  }
  prop_kernel<true, true><<<pblocks, 256, 0, stream>>>(zcur, h, d_out, rowptr, edges, dis, N);
}

// Round 4
// 833.629 us; speedup vs baseline: 3.0380x; 1.4841x over previous
//
#include <hip/hip_runtime.h>
#include <hip/hip_bf16.h>

#define ALPHA_F 0.1f
#define KSTEPS 10
#define BKT_SH 9                       // 512 dst rows per bucket
#define P1_CHUNK 8192

typedef __attribute__((ext_vector_type(8))) short bf16x8;
typedef __attribute__((ext_vector_type(4))) float f32x4;

__device__ __forceinline__ unsigned short f2bf(float f) {
  union { float f; unsigned int u; } v; v.f = f;
  unsigned int u = v.u;
  u += 0x7FFFu + ((u >> 16) & 1u);   // round-to-nearest-even
  return (unsigned short)(u >> 16);
}
__device__ __forceinline__ float bflo(unsigned int u) { return __uint_as_float(u << 16); }
__device__ __forceinline__ float bfhi(unsigned int u) { return __uint_as_float(u & 0xFFFF0000u); }

// ============ CSR build: two-level binned counting sort (no random 8B scatter) ============

// p0: global bucket histogram (LDS-aggregated)
__global__ __launch_bounds__(256)
void p0_hist(const int* __restrict__ dstv, int E, int* __restrict__ bhist) {
  __shared__ int h[256];
  int t = threadIdx.x;
  h[t] = 0;
  __syncthreads();
  int b0 = blockIdx.x * P1_CHUNK;
  int lim = min(P1_CHUNK, E - b0);
  for (int i = t; i < lim; i += 256) atomicAdd(&h[dstv[b0 + i] >> BKT_SH], 1);
  __syncthreads();
  if (h[t]) atomicAdd(&bhist[t], h[t]);
}

// p0_scan: exclusive scan of 256 bucket sizes -> bbase, gcur; rowptr[N]=E
__global__ void p0_scan(const int* __restrict__ bhist, int* __restrict__ bbase,
                        int* __restrict__ gcur, int* __restrict__ rowptr, int N, int E) {
  __shared__ int s[256];
  int t = threadIdx.x;
  int mine = bhist[t];
  s[t] = mine;
  __syncthreads();
  for (int off = 1; off < 256; off <<= 1) {
    int v = (t >= off) ? s[t - off] : 0;
    __syncthreads();
    s[t] += v;
    __syncthreads();
  }
  int excl = s[t] - mine;
  bbase[t] = excl;
  gcur[t] = excl;
  if (t == 0) rowptr[N] = E;
}

// p1: per-block local hist -> reserve contiguous sub-regions -> scatter (src,dst) to tmp
__global__ __launch_bounds__(256)
void p1_scatter(const int* __restrict__ srcv, const int* __restrict__ dstv, int E,
                int* __restrict__ gcur, int2* __restrict__ tmp) {
  __shared__ int h[256];
  __shared__ int loc[256];
  int t = threadIdx.x;
  int b0 = blockIdx.x * P1_CHUNK;
  int lim = min(P1_CHUNK, E - b0);
  h[t] = 0;
  __syncthreads();
  for (int i = t; i < lim; i += 256) atomicAdd(&h[dstv[b0 + i] >> BKT_SH], 1);
  __syncthreads();
  loc[t] = h[t] ? atomicAdd(&gcur[t], h[t]) : 0;
  __syncthreads();
  h[t] = 0;
  __syncthreads();
  for (int i = t; i < lim; i += 256) {
    int d = dstv[b0 + i], s = srcv[b0 + i];
    int b = d >> BKT_SH;
    int pos = loc[b] + atomicAdd(&h[b], 1);
    tmp[pos] = make_int2(s, d);
  }
}

// p2: one block per bucket — per-row hist/scan -> counts, rowptr, in-bucket sort
__global__ __launch_bounds__(256)
void p2_bucket(const int2* __restrict__ tmp, const int* __restrict__ bbase,
               const int* __restrict__ bhist, int* __restrict__ counts,
               int* __restrict__ rowptr, int2* __restrict__ out, int N) {
  __shared__ int h1[512];
  __shared__ int cur[512];
  __shared__ int s2[256];
  const int t = threadIdx.x;
  const int b = blockIdx.x;
  const int base = bbase[b];
  const int sz = bhist[b];
  const int r0 = b << BKT_SH;
  const int nrows = min(512, N - r0);

  h1[t] = 0; h1[t + 256] = 0;
  __syncthreads();
  for (int i = t; i < sz; i += 256) atomicAdd(&h1[tmp[base + i].y - r0], 1);
  __syncthreads();
  if (t < nrows) counts[r0 + t] = h1[t];
  if (t + 256 < nrows) counts[r0 + t + 256] = h1[t + 256];
  // exclusive scan of h1[0..512) into cur
  int a = h1[2 * t], c = h1[2 * t + 1];
  s2[t] = a + c;
  __syncthreads();
  for (int off = 1; off < 256; off <<= 1) {
    int v = (t >= off) ? s2[t - off] : 0;
    __syncthreads();
    s2[t] += v;
    __syncthreads();
  }
  int excl2 = s2[t] - (a + c);
  cur[2 * t] = excl2;
  cur[2 * t + 1] = excl2 + a;
  __syncthreads();
  if (t < nrows) rowptr[r0 + t] = base + cur[t];
  if (t + 256 < nrows) rowptr[r0 + t + 256] = base + cur[t + 256];
  __syncthreads();
  for (int i = t; i < sz; i += 256) {
    int2 e = tmp[base + i];
    int p = base + atomicAdd(&cur[e.y - r0], 1);
    out[p] = e;
  }
}

__global__ void k_dis(const int* __restrict__ counts, float* __restrict__ dis, int N) {
  int i = blockIdx.x * 256 + threadIdx.x;
  if (i < N) dis[i] = rsqrtf((float)(counts[i] + 1));  // +1 self-loop
}

// p3: in-place (src,dst) -> (src, weight_bits)
__global__ void p3_weights(int2* __restrict__ edges, const float* __restrict__ dis, int E) {
  int i = blockIdx.x * 256 + threadIdx.x;
  if (i >= E) return;
  int2 e = edges[i];
  edges[i] = make_int2(e.x, __float_as_int(dis[e.x] * dis[e.y]));
}

// ---------------- weight transpose + bf16 convert: WT[n][k] = bf16(W[k][n]) ----------------
__global__ void k_wconv(const float* __restrict__ W, unsigned short* __restrict__ WT,
                        int Kd, int Nd) {
  int idx = blockIdx.x * 256 + threadIdx.x;
  if (idx >= Kd * Nd) return;
  int n = idx / Kd, k = idx % Kd;
  WT[idx] = f2bf(W[(size_t)k * Nd + n]);
}

// ---------------- bf16 MFMA GEMM: out[M][BN] = A[M][Kd] * BT[BN][Kd]^T + bias ----------------
template<int BN, int WR, int WC, bool CONVERT_A, bool RELU, bool OUT_BF16>
__global__ __launch_bounds__(256)
void gemm_kernel(const void* __restrict__ Ag_, const unsigned short* __restrict__ BT,
                 const float* __restrict__ bias, void* __restrict__ out_,
                 int M, int Kd) {
  constexpr int MF = 64 / (16 * WR);
  constexpr int NF = BN / (16 * WC);
  __shared__ __align__(16) unsigned short As[64][40];
  __shared__ __align__(16) unsigned short Bs[BN][40];
  const int t = threadIdx.x;
  const int m0 = blockIdx.x * 64;
  const int lane = t & 63;
  const int w = t >> 6;
  const int wr = w / WC, wc = w % WC;
  const int lrow = t >> 2;
  const int lcb = t & 3;

  f32x4 acc[MF][NF] = {};

  for (int k0 = 0; k0 < Kd; k0 += 32) {
    {
      int gm = m0 + lrow;
      uint4 tv;
      unsigned short* tmp = (unsigned short*)&tv;
      if (CONVERT_A) {
        const float* A = (const float*)Ag_;
        if (gm < M) {
          const float* p = A + (size_t)gm * Kd + k0 + lcb * 8;
          float4 va = *(const float4*)p;
          float4 vb = *(const float4*)(p + 4);
          tmp[0] = f2bf(va.x); tmp[1] = f2bf(va.y); tmp[2] = f2bf(va.z); tmp[3] = f2bf(va.w);
          tmp[4] = f2bf(vb.x); tmp[5] = f2bf(vb.y); tmp[6] = f2bf(vb.z); tmp[7] = f2bf(vb.w);
        } else {
          tv = uint4{0, 0, 0, 0};
        }
      } else {
        const unsigned short* A = (const unsigned short*)Ag_;
        if (gm < M) tv = *(const uint4*)(A + (size_t)gm * Kd + k0 + lcb * 8);
        else        tv = uint4{0, 0, 0, 0};
      }
      *(uint4*)&As[lrow][lcb * 8] = tv;
    }
#pragma unroll
    for (int i = 0; i < BN / 64; ++i) {
      int ch = t + 256 * i;
      int row = ch >> 2, kc = (ch & 3) * 8;
      *(uint4*)&Bs[row][kc] = *(const uint4*)(BT + (size_t)row * Kd + k0 + kc);
    }
    __syncthreads();

    bf16x8 af[MF], bfv[NF];
#pragma unroll
    for (int mi = 0; mi < MF; ++mi)
      af[mi] = *(const bf16x8*)&As[wr * MF * 16 + mi * 16 + (lane & 15)][(lane >> 4) * 8];
#pragma unroll
    for (int ni = 0; ni < NF; ++ni)
      bfv[ni] = *(const bf16x8*)&Bs[wc * NF * 16 + ni * 16 + (lane & 15)][(lane >> 4) * 8];
#pragma unroll
    for (int mi = 0; mi < MF; ++mi)
#pragma unroll
      for (int ni = 0; ni < NF; ++ni)
        acc[mi][ni] = __builtin_amdgcn_mfma_f32_16x16x32_bf16(af[mi], bfv[ni], acc[mi][ni], 0, 0, 0);
    __syncthreads();
  }

  float* outf = (float*)out_;
  unsigned short* outb = (unsigned short*)out_;
#pragma unroll
  for (int mi = 0; mi < MF; ++mi) {
#pragma unroll
    for (int ni = 0; ni < NF; ++ni) {
      int gn = wc * NF * 16 + ni * 16 + (lane & 15);
      float bv = bias[gn];
#pragma unroll
      for (int j = 0; j < 4; ++j) {
        int gm = m0 + wr * MF * 16 + mi * 16 + (lane >> 4) * 4 + j;
        if (gm < M) {
          float v = acc[mi][ni][j] + bv;
          if (RELU) v = fmaxf(v, 0.f);
          if (OUT_BF16) outb[(size_t)gm * BN + gn] = f2bf(v);
          else          outf[(size_t)gm * BN + gn] = v;
        }
      }
    }
  }
}

// ---------------- PPR diffusion: one wave per dst row ----------------
// 8 lanes per edge (16B z-slice each), 8 edges per wave-iteration.
// z and h both bf16 [N][64]. FINAL: fuse log_softmax, write f32.
template<bool FINAL>
__global__ __launch_bounds__(256)
void prop_kernel(const unsigned short* __restrict__ zin,
                 const unsigned short* __restrict__ hb,
                 void* __restrict__ zout, const int* __restrict__ rowptr,
                 const int2* __restrict__ edges, const float* __restrict__ dis, int N) {
  int wid = (blockIdx.x * 256 + threadIdx.x) >> 6;
  wid = __builtin_amdgcn_readfirstlane(wid);   // wave-uniform -> scalar loads
  if (wid >= N) return;
  const int lane = threadIdx.x & 63;
  const int g  = lane >> 3;
  const int lg = lane & 7;
  const int r = wid;

  float acc[8] = {0.f, 0.f, 0.f, 0.f, 0.f, 0.f, 0.f, 0.f};
  const int start = rowptr[r], end = rowptr[r + 1];
  for (int e = start; e < end; e += 64) {
    int na = end - e; if (na > 64) na = 64;
    int2 ed = make_int2(0, 0);                 // pad: w==0 -> contributes 0
    if (lane < na) ed = edges[e + lane];
#pragma unroll 4
    for (int j = 0; j < na; j += 8) {
      int jj = j + g;
      int cj = __shfl(ed.x, jj);
      float wj = __shfl(__int_as_float(ed.y), jj);
      uint4 zr = *(const uint4*)(zin + (size_t)cj * 64 + 8 * lg);
      acc[0] += wj * bflo(zr.x); acc[1] += wj * bfhi(zr.x);
      acc[2] += wj * bflo(zr.y); acc[3] += wj * bfhi(zr.y);
      acc[4] += wj * bflo(zr.z); acc[5] += wj * bfhi(zr.z);
      acc[6] += wj * bflo(zr.w); acc[7] += wj * bfhi(zr.w);
    }
  }
#pragma unroll
  for (int k = 0; k < 8; ++k) {
    acc[k] += __shfl_xor(acc[k], 8);
    acc[k] += __shfl_xor(acc[k], 16);
    acc[k] += __shfl_xor(acc[k], 32);
  }

  float dr = dis[r];
  float sw = dr * dr;
  uint4 zs = *(const uint4*)(zin + (size_t)r * 64 + 8 * lg);
  uint4 hr = *(const uint4*)(hb + (size_t)r * 64 + 8 * lg);
  float selfz[8] = { bflo(zs.x), bfhi(zs.x), bflo(zs.y), bfhi(zs.y),
                     bflo(zs.z), bfhi(zs.z), bflo(zs.w), bfhi(zs.w) };
  float hv[8]    = { bflo(hr.x), bfhi(hr.x), bflo(hr.y), bfhi(hr.y),
                     bflo(hr.z), bfhi(hr.z), bflo(hr.w), bfhi(hr.w) };
  float f[8];
#pragma unroll
  for (int k = 0; k < 8; ++k)
    f[k] = ALPHA_F * hv[k] + (1.f - ALPHA_F) * (acc[k] + sw * selfz[k]);

  if (!FINAL) {
    if (g == 0) {
      uint4 o;
      o.x = (unsigned)f2bf(f[0]) | ((unsigned)f2bf(f[1]) << 16);
      o.y = (unsigned)f2bf(f[2]) | ((unsigned)f2bf(f[3]) << 16);
      o.z = (unsigned)f2bf(f[4]) | ((unsigned)f2bf(f[5]) << 16);
      o.w = (unsigned)f2bf(f[6]) | ((unsigned)f2bf(f[7]) << 16);
      *(uint4*)((unsigned short*)zout + (size_t)r * 64 + 8 * lg) = o;
    }
  } else {
    float m = f[0];
#pragma unroll
    for (int k = 1; k < 8; ++k) m = fmaxf(m, f[k]);
    m = fmaxf(m, __shfl_xor(m, 1));
    m = fmaxf(m, __shfl_xor(m, 2));
    m = fmaxf(m, __shfl_xor(m, 4));
    float s = 0.f;
#pragma unroll
    for (int k = 0; k < 8; ++k) s += __expf(f[k] - m);
    s += __shfl_xor(s, 1);
    s += __shfl_xor(s, 2);
    s += __shfl_xor(s, 4);
    float ls = __logf(s);
    if (g == 0) {
      float* op = (float*)zout + (size_t)r * 64 + 8 * lg;
      *(float4*)op       = make_float4(f[0] - m - ls, f[1] - m - ls, f[2] - m - ls, f[3] - m - ls);
      *(float4*)(op + 4) = make_float4(f[4] - m - ls, f[5] - m - ls, f[6] - m - ls, f[7] - m - ls);
    }
  }
}

extern "C" void kernel_launch(void* const* d_in, const int* in_sizes, int n_in,
                              void* d_out, int out_size, void* d_ws, size_t ws_size,
                              hipStream_t stream) {
  const float* x  = (const float*)d_in[0];
  const int*   ei = (const int*)d_in[1];
  const float* W1 = (const float*)d_in[2];
  const float* b1 = (const float*)d_in[3];
  const float* W2 = (const float*)d_in[4];
  const float* b2 = (const float*)d_in[5];

  const int IN = 512, HID = 256, OUT = 64;
  const int N = in_sizes[0] / IN;
  const int E = in_sizes[1] / 2;
  const int* srcv = ei;
  const int* dstv = ei + E;
  const int NBUCK = (N + (1 << BKT_SH) - 1) >> BKT_SH;   // <= 256 required

  char* p = (char*)d_ws;
  auto alloc = [&](size_t bytes) -> void* {
    void* r = (void*)p;
    p += (bytes + 255) & ~(size_t)255;
    return r;
  };
  int*   bhist  = (int*)alloc(256 * 4);
  int*   bbase  = (int*)alloc(256 * 4);
  int*   gcur   = (int*)alloc(256 * 4);
  int*   counts = (int*)alloc((size_t)N * 4);
  float* dis    = (float*)alloc((size_t)N * 4);
  int*   rowptr = (int*)alloc((size_t)(N + 1) * 4);
  int2*  edges  = (int2*)alloc((size_t)E * 8);
  unsigned short* WT1 = (unsigned short*)alloc((size_t)IN * HID * 2);
  unsigned short* WT2 = (unsigned short*)alloc((size_t)HID * OUT * 2);
  unsigned short* hidb = (unsigned short*)alloc((size_t)N * HID * 2);  // 51.2 MB
  unsigned short* hb   = (unsigned short*)alloc((size_t)N * OUT * 2);  // bf16 h
  // overlays of hidb (dead by the time each user runs):
  int2* tmp = (int2*)hidb;                       // binned edges (25.6 MB) — dead before gemm1
  unsigned short* zA = hidb;                     // z ping-pong — alive only after gemm2
  unsigned short* zB = hidb + (size_t)N * OUT;

  hipMemsetAsync(bhist, 0, 256 * 4, stream);

  const int p1blocks = (E + P1_CHUNK - 1) / P1_CHUNK;
  p0_hist<<<p1blocks, 256, 0, stream>>>(dstv, E, bhist);
  p0_scan<<<1, 256, 0, stream>>>(bhist, bbase, gcur, rowptr, N, E);
  p1_scatter<<<p1blocks, 256, 0, stream>>>(srcv, dstv, E, gcur, tmp);
  p2_bucket<<<NBUCK, 256, 0, stream>>>(tmp, bbase, bhist, counts, rowptr, edges, N);
  k_dis<<<(N + 255) / 256, 256, 0, stream>>>(counts, dis, N);
  p3_weights<<<(E + 255) / 256, 256, 0, stream>>>(edges, dis, E);

  k_wconv<<<(IN * HID + 255) / 256, 256, 0, stream>>>(W1, WT1, IN, HID);
  k_wconv<<<(HID * OUT + 255) / 256, 256, 0, stream>>>(W2, WT2, HID, OUT);

  const int gblocks = (N + 63) / 64;
  gemm_kernel<256, 1, 4, true, true, true><<<gblocks, 256, 0, stream>>>(
      x, WT1, b1, hidb, N, IN);
  gemm_kernel<64, 2, 2, false, false, true><<<gblocks, 256, 0, stream>>>(
      hidb, WT2, b2, hb, N, HID);

  const int pblocks = (N + 3) / 4;
  const unsigned short* zcur = hb;               // z0 = h
  for (int it = 0; it < KSTEPS - 1; ++it) {
    unsigned short* znext = (it & 1) ? zB : zA;
    prop_kernel<false><<<pblocks, 256, 0, stream>>>(zcur, hb, znext, rowptr, edges, dis, N);
    zcur = znext;
  }
  prop_kernel<true><<<pblocks, 256, 0, stream>>>(zcur, hb, d_out, rowptr, edges, dis, N);
}

// Round 5
// 820.196 us; speedup vs baseline: 3.0878x; 1.0164x over previous
//
#include <hip/hip_runtime.h>
#include <hip/hip_bf16.h>

#define ALPHA_F 0.1f
#define KSTEPS 10
#define BKT_SH 9                       // 512 dst rows per bucket
#define P1_CHUNK 8192

typedef __attribute__((ext_vector_type(8))) short bf16x8;
typedef __attribute__((ext_vector_type(4))) float f32x4;

__device__ __forceinline__ unsigned short f2bf(float f) {
  union { float f; unsigned int u; } v; v.f = f;
  unsigned int u = v.u;
  u += 0x7FFFu + ((u >> 16) & 1u);   // round-to-nearest-even
  return (unsigned short)(u >> 16);
}
__device__ __forceinline__ float bflo(unsigned int u) { return __uint_as_float(u << 16); }
__device__ __forceinline__ float bfhi(unsigned int u) { return __uint_as_float(u & 0xFFFF0000u); }

__device__ __forceinline__ void gload16(const void* g, void* l) {
  __builtin_amdgcn_global_load_lds(
      (const __attribute__((address_space(1))) void*)g,
      (__attribute__((address_space(3))) void*)l, 16, 0, 0);
}

// ============ CSR build: two-level binned counting sort ============

__global__ __launch_bounds__(256)
void p0_hist(const int* __restrict__ dstv, int E, int* __restrict__ bhist) {
  __shared__ int h[256];
  int t = threadIdx.x;
  h[t] = 0;
  __syncthreads();
  int b0 = blockIdx.x * P1_CHUNK;
  int lim = min(P1_CHUNK, E - b0);
  for (int i = t; i < lim; i += 256) atomicAdd(&h[dstv[b0 + i] >> BKT_SH], 1);
  __syncthreads();
  if (h[t]) atomicAdd(&bhist[t], h[t]);
}

__global__ void p0_scan(const int* __restrict__ bhist, int* __restrict__ bbase,
                        int* __restrict__ gcur, int* __restrict__ rowptr, int N, int E) {
  __shared__ int s[256];
  int t = threadIdx.x;
  int mine = bhist[t];
  s[t] = mine;
  __syncthreads();
  for (int off = 1; off < 256; off <<= 1) {
    int v = (t >= off) ? s[t - off] : 0;
    __syncthreads();
    s[t] += v;
    __syncthreads();
  }
  int excl = s[t] - mine;
  bbase[t] = excl;
  gcur[t] = excl;
  if (t == 0) rowptr[N] = E;
}

__global__ __launch_bounds__(256)
void p1_scatter(const int* __restrict__ srcv, const int* __restrict__ dstv, int E,
                int* __restrict__ gcur, int2* __restrict__ tmp) {
  __shared__ int h[256];
  __shared__ int loc[256];
  int t = threadIdx.x;
  int b0 = blockIdx.x * P1_CHUNK;
  int lim = min(P1_CHUNK, E - b0);
  h[t] = 0;
  __syncthreads();
  for (int i = t; i < lim; i += 256) atomicAdd(&h[dstv[b0 + i] >> BKT_SH], 1);
  __syncthreads();
  loc[t] = h[t] ? atomicAdd(&gcur[t], h[t]) : 0;
  __syncthreads();
  h[t] = 0;
  __syncthreads();
  for (int i = t; i < lim; i += 256) {
    int d = dstv[b0 + i], s = srcv[b0 + i];
    int b = d >> BKT_SH;
    int pos = loc[b] + atomicAdd(&h[b], 1);
    tmp[pos] = make_int2(s, d);
  }
}

__global__ __launch_bounds__(256)
void p2_bucket(const int2* __restrict__ tmp, const int* __restrict__ bbase,
               const int* __restrict__ bhist, int* __restrict__ counts,
               int* __restrict__ rowptr, int2* __restrict__ out, int N) {
  __shared__ int h1[512];
  __shared__ int cur[512];
  __shared__ int s2[256];
  const int t = threadIdx.x;
  const int b = blockIdx.x;
  const int base = bbase[b];
  const int sz = bhist[b];
  const int r0 = b << BKT_SH;
  const int nrows = min(512, N - r0);

  h1[t] = 0; h1[t + 256] = 0;
  __syncthreads();
  for (int i = t; i < sz; i += 256) atomicAdd(&h1[tmp[base + i].y - r0], 1);
  __syncthreads();
  if (t < nrows) counts[r0 + t] = h1[t];
  if (t + 256 < nrows) counts[r0 + t + 256] = h1[t + 256];
  int a = h1[2 * t], c = h1[2 * t + 1];
  s2[t] = a + c;
  __syncthreads();
  for (int off = 1; off < 256; off <<= 1) {
    int v = (t >= off) ? s2[t - off] : 0;
    __syncthreads();
    s2[t] += v;
    __syncthreads();
  }
  int excl2 = s2[t] - (a + c);
  cur[2 * t] = excl2;
  cur[2 * t + 1] = excl2 + a;
  __syncthreads();
  if (t < nrows) rowptr[r0 + t] = base + cur[t];
  if (t + 256 < nrows) rowptr[r0 + t + 256] = base + cur[t + 256];
  __syncthreads();
  for (int i = t; i < sz; i += 256) {
    int2 e = tmp[base + i];
    int p = base + atomicAdd(&cur[e.y - r0], 1);
    out[p] = e;
  }
}

__global__ void k_dis(const int* __restrict__ counts, float* __restrict__ dis, int N) {
  int i = blockIdx.x * 256 + threadIdx.x;
  if (i < N) dis[i] = rsqrtf((float)(counts[i] + 1));  // +1 self-loop
}

__global__ void p3_weights(int2* __restrict__ edges, const float* __restrict__ dis, int E) {
  int i = blockIdx.x * 256 + threadIdx.x;
  if (i >= E) return;
  int2 e = edges[i];
  edges[i] = make_int2(e.x, __float_as_int(dis[e.x] * dis[e.y]));
}

// ============ weight conversion to MFMA-native tiled layouts ============
// B-tile layout per K-step: [nsub][q][n16][e8]  (elem k = kstep*64+q*8+e, col = nsub*16+n)

// W1 [512][256] -> WT1t: [kstep8][nsub16][q8][n16][e8]
__global__ void k_wconv1(const float* __restrict__ W, unsigned short* __restrict__ WT) {
  int idx = blockIdx.x * 256 + threadIdx.x;
  if (idx >= 512 * 256) return;
  int e = idx & 7, n = (idx >> 3) & 15, q = (idx >> 7) & 7;
  int nsub = (idx >> 10) & 15, kstep = idx >> 14;
  int k = kstep * 64 + q * 8 + e;
  int ncol = nsub * 16 + n;
  WT[idx] = f2bf(W[(size_t)k * 256 + ncol]);
}

// W2 [256][64] -> WT2t: [kstep4][nsub4][q8][n16][e8]
__global__ void k_wconv2(const float* __restrict__ W, unsigned short* __restrict__ WT) {
  int idx = blockIdx.x * 256 + threadIdx.x;
  if (idx >= 256 * 64) return;
  int e = idx & 7, n = (idx >> 3) & 15, q = (idx >> 7) & 7;
  int nsub = (idx >> 10) & 3, kstep = idx >> 12;
  int k = kstep * 64 + q * 8 + e;
  int ncol = nsub * 16 + n;
  WT[idx] = f2bf(W[(size_t)k * 64 + ncol]);
}

// ============ GEMM1: hid_tiled = relu(x @ W1 + b1), BM=128 BN=256 BK=64 ============
// 512 threads = 8 waves (2m x 4n), wave tile 64x64 (4x4 of 16x16x32).
// LDS fragment-native: A [msub8][q8][m16][e8], B [nsub16][q8][n16][e8] -> all ds ops linear.
// Output written in GEMM2's A-tiled layout: per mtile [kstep4][msub8][q8][m16][e8].
__global__ __launch_bounds__(512)
void gemm1_kernel(const float* __restrict__ X, const unsigned short* __restrict__ Bt,
                  const float* __restrict__ bias, unsigned short* __restrict__ outT,
                  int M) {
  __shared__ __align__(16) unsigned short Al[8192];    // 16 KB
  __shared__ __align__(16) unsigned short Bl[16384];   // 32 KB
  const int t = threadIdx.x;
  const int m0 = blockIdx.x * 128;
  const int lane = t & 63;
  const int w = t >> 6;
  const int wm = w >> 2, wn = w & 3;

  // A staging: thread t owns slots t and t+512; slot s = msub*128 + q*16 + m
  const int sm = ((t >> 7) << 4) + (t & 15);   // msub*16 + m  (msub = t>>7 in 0..3)
  const int sq = (t >> 4) & 7;
  const int r1 = m0 + sm;
  const int r2 = r1 + 64;                      // slot t+512 -> msub+4
  const bool g1 = r1 < M, g2 = r2 < M;

  f32x4 acc[4][4] = {};

  for (int ks = 0; ks < 8; ++ks) {
    const int kc = ks * 64 + sq * 8;
    uint4 v1 = {0, 0, 0, 0}, v2 = {0, 0, 0, 0};
    if (g1) {
      const float* p = X + (size_t)r1 * 512 + kc;
      float4 a = *(const float4*)p, b = *(const float4*)(p + 4);
      unsigned short* o = (unsigned short*)&v1;
      o[0] = f2bf(a.x); o[1] = f2bf(a.y); o[2] = f2bf(a.z); o[3] = f2bf(a.w);
      o[4] = f2bf(b.x); o[5] = f2bf(b.y); o[6] = f2bf(b.z); o[7] = f2bf(b.w);
    }
    if (g2) {
      const float* p = X + (size_t)r2 * 512 + kc;
      float4 a = *(const float4*)p, b = *(const float4*)(p + 4);
      unsigned short* o = (unsigned short*)&v2;
      o[0] = f2bf(a.x); o[1] = f2bf(a.y); o[2] = f2bf(a.z); o[3] = f2bf(a.w);
      o[4] = f2bf(b.x); o[5] = f2bf(b.y); o[6] = f2bf(b.z); o[7] = f2bf(b.w);
    }
    *(uint4*)&Al[t * 8] = v1;
    *(uint4*)&Al[(t + 512) * 8] = v2;

    const unsigned short* bs = Bt + ks * 16384;
    gload16(bs + (size_t)t * 8,          &Bl[t * 8]);
    gload16(bs + (size_t)(t + 512) * 8,  &Bl[(t + 512) * 8]);
    gload16(bs + (size_t)(t + 1024) * 8, &Bl[(t + 1024) * 8]);
    gload16(bs + (size_t)(t + 1536) * 8, &Bl[(t + 1536) * 8]);
    __syncthreads();

#pragma unroll
    for (int kk = 0; kk < 2; ++kk) {
      bf16x8 af[4], bfv[4];
#pragma unroll
      for (int mi = 0; mi < 4; ++mi)
        af[mi] = *(const bf16x8*)&Al[((wm * 4 + mi) * 128 + kk * 64 + (lane >> 4) * 16 + (lane & 15)) * 8];
#pragma unroll
      for (int ni = 0; ni < 4; ++ni)
        bfv[ni] = *(const bf16x8*)&Bl[((wn * 4 + ni) * 128 + kk * 64 + (lane >> 4) * 16 + (lane & 15)) * 8];
#pragma unroll
      for (int mi = 0; mi < 4; ++mi)
#pragma unroll
        for (int ni = 0; ni < 4; ++ni)
          acc[mi][ni] = __builtin_amdgcn_mfma_f32_16x16x32_bf16(af[mi], bfv[ni], acc[mi][ni], 0, 0, 0);
    }
    __syncthreads();
  }

  // epilogue: relu + bias, write into GEMM2 A-tiled layout
  unsigned short* ob = outT + (size_t)blockIdx.x * 32768;
#pragma unroll
  for (int mi = 0; mi < 4; ++mi) {
#pragma unroll
    for (int ni = 0; ni < 4; ++ni) {
      int n = wn * 64 + ni * 16 + (lane & 15);
      float bv = bias[n];
      int kstep = n >> 6, q = (n >> 3) & 7, e = n & 7;
#pragma unroll
      for (int j = 0; j < 4; ++j) {
        int lm = wm * 64 + mi * 16 + (lane >> 4) * 4 + j;
        if (m0 + lm < M) {
          float v = fmaxf(acc[mi][ni][j] + bv, 0.f);
          int msub = lm >> 4, mm = lm & 15;
          ob[((((kstep * 8 + msub) * 8 + q) * 16 + mm) * 8) + e] = f2bf(v);
        }
      }
    }
  }
}

// ============ GEMM2: hb = hid @ W2 + b2, BM=128 BN=64 BK=64, pure global_load_lds ============
// 256 threads = 4 waves (2m x 2n), wave tile 64x32 (4x2 of 16x16x32).
__global__ __launch_bounds__(256)
void gemm2_kernel(const unsigned short* __restrict__ At, const unsigned short* __restrict__ Bt,
                  const float* __restrict__ bias, unsigned short* __restrict__ hb, int M) {
  __shared__ __align__(16) unsigned short Al[8192];   // 16 KB
  __shared__ __align__(16) unsigned short Bl[4096];   // 8 KB
  const int t = threadIdx.x;
  const int m0 = blockIdx.x * 128;
  const int lane = t & 63;
  const int w = t >> 6;
  const int wm = w >> 1, wn = w & 1;

  f32x4 acc[4][2] = {};

  const unsigned short* ab = At + (size_t)blockIdx.x * 32768;
  for (int ks = 0; ks < 4; ++ks) {
    const unsigned short* as = ab + ks * 8192;
    gload16(as + (size_t)t * 8,         &Al[t * 8]);
    gload16(as + (size_t)(t + 256) * 8, &Al[(t + 256) * 8]);
    gload16(as + (size_t)(t + 512) * 8, &Al[(t + 512) * 8]);
    gload16(as + (size_t)(t + 768) * 8, &Al[(t + 768) * 8]);
    const unsigned short* bs = Bt + ks * 4096;
    gload16(bs + (size_t)t * 8,         &Bl[t * 8]);
    gload16(bs + (size_t)(t + 256) * 8, &Bl[(t + 256) * 8]);
    __syncthreads();

#pragma unroll
    for (int kk = 0; kk < 2; ++kk) {
      bf16x8 af[4], bfv[2];
#pragma unroll
      for (int mi = 0; mi < 4; ++mi)
        af[mi] = *(const bf16x8*)&Al[((wm * 4 + mi) * 128 + kk * 64 + (lane >> 4) * 16 + (lane & 15)) * 8];
#pragma unroll
      for (int ni = 0; ni < 2; ++ni)
        bfv[ni] = *(const bf16x8*)&Bl[((wn * 2 + ni) * 128 + kk * 64 + (lane >> 4) * 16 + (lane & 15)) * 8];
#pragma unroll
      for (int mi = 0; mi < 4; ++mi)
#pragma unroll
        for (int ni = 0; ni < 2; ++ni)
          acc[mi][ni] = __builtin_amdgcn_mfma_f32_16x16x32_bf16(af[mi], bfv[ni], acc[mi][ni], 0, 0, 0);
    }
    __syncthreads();
  }

#pragma unroll
  for (int mi = 0; mi < 4; ++mi) {
#pragma unroll
    for (int ni = 0; ni < 2; ++ni) {
      int gn = wn * 32 + ni * 16 + (lane & 15);
      float bv = bias[gn];
#pragma unroll
      for (int j = 0; j < 4; ++j) {
        int gm = m0 + wm * 64 + mi * 16 + (lane >> 4) * 4 + j;
        if (gm < M) hb[(size_t)gm * 64 + gn] = f2bf(acc[mi][ni][j] + bv);
      }
    }
  }
}

// ---------------- PPR diffusion: one wave per dst row ----------------
template<bool FINAL>
__global__ __launch_bounds__(256)
void prop_kernel(const unsigned short* __restrict__ zin,
                 const unsigned short* __restrict__ hb,
                 void* __restrict__ zout, const int* __restrict__ rowptr,
                 const int2* __restrict__ edges, const float* __restrict__ dis, int N) {
  int wid = (blockIdx.x * 256 + threadIdx.x) >> 6;
  wid = __builtin_amdgcn_readfirstlane(wid);
  if (wid >= N) return;
  const int lane = threadIdx.x & 63;
  const int g  = lane >> 3;
  const int lg = lane & 7;
  const int r = wid;

  float acc[8] = {0.f, 0.f, 0.f, 0.f, 0.f, 0.f, 0.f, 0.f};
  const int start = rowptr[r], end = rowptr[r + 1];
  for (int e = start; e < end; e += 64) {
    int na = end - e; if (na > 64) na = 64;
    int2 ed = make_int2(0, 0);
    if (lane < na) ed = edges[e + lane];
#pragma unroll 4
    for (int j = 0; j < na; j += 8) {
      int jj = j + g;
      int cj = __shfl(ed.x, jj);
      float wj = __shfl(__int_as_float(ed.y), jj);
      uint4 zr = *(const uint4*)(zin + (size_t)cj * 64 + 8 * lg);
      acc[0] += wj * bflo(zr.x); acc[1] += wj * bfhi(zr.x);
      acc[2] += wj * bflo(zr.y); acc[3] += wj * bfhi(zr.y);
      acc[4] += wj * bflo(zr.z); acc[5] += wj * bfhi(zr.z);
      acc[6] += wj * bflo(zr.w); acc[7] += wj * bfhi(zr.w);
    }
  }
#pragma unroll
  for (int k = 0; k < 8; ++k) {
    acc[k] += __shfl_xor(acc[k], 8);
    acc[k] += __shfl_xor(acc[k], 16);
    acc[k] += __shfl_xor(acc[k], 32);
  }

  float dr = dis[r];
  float sw = dr * dr;
  uint4 zs = *(const uint4*)(zin + (size_t)r * 64 + 8 * lg);
  uint4 hr = *(const uint4*)(hb + (size_t)r * 64 + 8 * lg);
  float selfz[8] = { bflo(zs.x), bfhi(zs.x), bflo(zs.y), bfhi(zs.y),
                     bflo(zs.z), bfhi(zs.z), bflo(zs.w), bfhi(zs.w) };
  float hv[8]    = { bflo(hr.x), bfhi(hr.x), bflo(hr.y), bfhi(hr.y),
                     bflo(hr.z), bfhi(hr.z), bflo(hr.w), bfhi(hr.w) };
  float f[8];
#pragma unroll
  for (int k = 0; k < 8; ++k)
    f[k] = ALPHA_F * hv[k] + (1.f - ALPHA_F) * (acc[k] + sw * selfz[k]);

  if (!FINAL) {
    if (g == 0) {
      uint4 o;
      o.x = (unsigned)f2bf(f[0]) | ((unsigned)f2bf(f[1]) << 16);
      o.y = (unsigned)f2bf(f[2]) | ((unsigned)f2bf(f[3]) << 16);
      o.z = (unsigned)f2bf(f[4]) | ((unsigned)f2bf(f[5]) << 16);
      o.w = (unsigned)f2bf(f[6]) | ((unsigned)f2bf(f[7]) << 16);
      *(uint4*)((unsigned short*)zout + (size_t)r * 64 + 8 * lg) = o;
    }
  } else {
    float m = f[0];
#pragma unroll
    for (int k = 1; k < 8; ++k) m = fmaxf(m, f[k]);
    m = fmaxf(m, __shfl_xor(m, 1));
    m = fmaxf(m, __shfl_xor(m, 2));
    m = fmaxf(m, __shfl_xor(m, 4));
    float s = 0.f;
#pragma unroll
    for (int k = 0; k < 8; ++k) s += __expf(f[k] - m);
    s += __shfl_xor(s, 1);
    s += __shfl_xor(s, 2);
    s += __shfl_xor(s, 4);
    float ls = __logf(s);
    if (g == 0) {
      float* op = (float*)zout + (size_t)r * 64 + 8 * lg;
      *(float4*)op       = make_float4(f[0] - m - ls, f[1] - m - ls, f[2] - m - ls, f[3] - m - ls);
      *(float4*)(op + 4) = make_float4(f[4] - m - ls, f[5] - m - ls, f[6] - m - ls, f[7] - m - ls);
    }
  }
}

extern "C" void kernel_launch(void* const* d_in, const int* in_sizes, int n_in,
                              void* d_out, int out_size, void* d_ws, size_t ws_size,
                              hipStream_t stream) {
  const float* x  = (const float*)d_in[0];
  const int*   ei = (const int*)d_in[1];
  const float* W1 = (const float*)d_in[2];
  const float* b1 = (const float*)d_in[3];
  const float* W2 = (const float*)d_in[4];
  const float* b2 = (const float*)d_in[5];

  const int IN = 512, HID = 256, OUT = 64;
  const int N = in_sizes[0] / IN;
  const int E = in_sizes[1] / 2;
  const int* srcv = ei;
  const int* dstv = ei + E;
  const int NBUCK = (N + (1 << BKT_SH) - 1) >> BKT_SH;
  const int MT = (N + 127) / 128;                 // M-tiles of 128

  char* p = (char*)d_ws;
  auto alloc = [&](size_t bytes) -> void* {
    void* r = (void*)p;
    p += (bytes + 255) & ~(size_t)255;
    return r;
  };
  int*   bhist  = (int*)alloc(256 * 4);
  int*   bbase  = (int*)alloc(256 * 4);
  int*   gcur   = (int*)alloc(256 * 4);
  int*   counts = (int*)alloc((size_t)N * 4);
  float* dis    = (float*)alloc((size_t)N * 4);
  int*   rowptr = (int*)alloc((size_t)(N + 1) * 4);
  int2*  edges  = (int2*)alloc((size_t)E * 8);
  unsigned short* WT1t = (unsigned short*)alloc((size_t)IN * HID * 2);
  unsigned short* WT2t = (unsigned short*)alloc((size_t)HID * OUT * 2);
  unsigned short* hidT = (unsigned short*)alloc((size_t)MT * 32768 * 2);  // tiled hidden
  unsigned short* hb   = (unsigned short*)alloc((size_t)N * OUT * 2);     // bf16 h row-major
  // overlays of hidT (dead by the time each user runs):
  int2* tmp = (int2*)hidT;                       // binned edges — dead before gemm1
  unsigned short* zA = hidT;                     // z ping-pong — alive only after gemm2
  unsigned short* zB = hidT + (size_t)N * OUT;

  hipMemsetAsync(bhist, 0, 256 * 4, stream);

  const int p1blocks = (E + P1_CHUNK - 1) / P1_CHUNK;
  p0_hist<<<p1blocks, 256, 0, stream>>>(dstv, E, bhist);
  p0_scan<<<1, 256, 0, stream>>>(bhist, bbase, gcur, rowptr, N, E);
  p1_scatter<<<p1blocks, 256, 0, stream>>>(srcv, dstv, E, gcur, tmp);
  p2_bucket<<<NBUCK, 256, 0, stream>>>(tmp, bbase, bhist, counts, rowptr, edges, N);
  k_dis<<<(N + 255) / 256, 256, 0, stream>>>(counts, dis, N);
  p3_weights<<<(E + 255) / 256, 256, 0, stream>>>(edges, dis, E);

  k_wconv1<<<(IN * HID + 255) / 256, 256, 0, stream>>>(W1, WT1t);
  k_wconv2<<<(HID * OUT + 255) / 256, 256, 0, stream>>>(W2, WT2t);

  gemm1_kernel<<<MT, 512, 0, stream>>>(x, WT1t, b1, hidT, N);
  gemm2_kernel<<<MT, 256, 0, stream>>>(hidT, WT2t, b2, hb, N);

  const int pblocks = (N + 3) / 4;
  const unsigned short* zcur = hb;               // z0 = h
  for (int it = 0; it < KSTEPS - 1; ++it) {
    unsigned short* znext = (it & 1) ? zB : zA;
    prop_kernel<false><<<pblocks, 256, 0, stream>>>(zcur, hb, znext, rowptr, edges, dis, N);
    zcur = znext;
  }
  prop_kernel<true><<<pblocks, 256, 0, stream>>>(zcur, hb, d_out, rowptr, edges, dis, N);
}